// Round 1
// baseline (568.906 us; speedup 1.0000x reference)
//
#include <hip/hip_runtime.h>
#include <math.h>

// Problem constants
#define NN 30000
#define NE 480000
#define FIN 256
#define DH 32
#define NH 4
#define NC 47

static inline size_t align256(size_t x) { return (x + 255) & ~(size_t)255; }

// ---------------- CSR build ----------------
__global__ void count_k(const int* __restrict__ dst, int* __restrict__ cnt, int E) {
    int e = blockIdx.x * blockDim.x + threadIdx.x;
    if (e < E) atomicAdd(&cnt[dst[e]], 1);
}

__global__ __launch_bounds__(1024) void scan_k(const int* __restrict__ cnt,
                                               int* __restrict__ offs, int n) {
    __shared__ int warp_sums[16];
    __shared__ int carry_s;
    const int lane = threadIdx.x & 63;
    const int wid = threadIdx.x >> 6;
    if (threadIdx.x == 0) carry_s = 0;
    __syncthreads();
    for (int base = 0; base < n; base += 1024) {
        int i = base + threadIdx.x;
        int v = (i < n) ? cnt[i] : 0;
        int x = v;
        #pragma unroll
        for (int off = 1; off < 64; off <<= 1) {
            int y = __shfl_up(x, off);
            if (lane >= off) x += y;
        }
        if (lane == 63) warp_sums[wid] = x;
        __syncthreads();
        if (wid == 0) {
            int ws = (lane < 16) ? warp_sums[lane] : 0;
            #pragma unroll
            for (int off = 1; off < 16; off <<= 1) {
                int y = __shfl_up(ws, off);
                if (lane >= off) ws += y;
            }
            if (lane < 16) warp_sums[lane] = ws;
        }
        __syncthreads();
        int wbase = (wid > 0) ? warp_sums[wid - 1] : 0;
        int incl = x + wbase + carry_s;
        if (i < n) offs[i] = incl - v;  // exclusive
        __syncthreads();
        if (threadIdx.x == 1023) carry_s = incl;
        __syncthreads();
    }
    if (threadIdx.x == 0) offs[n] = carry_s;
}

__global__ void fill_k(const int* __restrict__ dst, int* __restrict__ cursor,
                       int* __restrict__ eidx, int E) {
    int e = blockIdx.x * blockDim.x + threadIdx.x;
    if (e < E) {
        int p = atomicAdd(&cursor[dst[e]], 1);
        eidx[p] = e;
    }
}

// ---------------- f32 GEMM: C[N,M] = A[N,K] @ B[K,M], 64x64 tile ----------------
__global__ __launch_bounds__(256) void gemm64(const float* __restrict__ A,
                                              const float* __restrict__ B,
                                              float* __restrict__ C,
                                              int N, int K, int M) {
    __shared__ float As[32][68];
    __shared__ float Bs[32][68];
    const int tid = threadIdx.x;
    const int tx = tid & 15;   // col group (4 cols)
    const int ty = tid >> 4;   // row group (4 rows)
    const int row0 = blockIdx.x * 64;
    const int col0 = blockIdx.y * 64;
    float acc[4][4] = {};
    for (int k0 = 0; k0 < K; k0 += 32) {
        #pragma unroll
        for (int i = tid; i < 64 * 32; i += 256) {
            int r = i >> 5, kk = i & 31;
            int gr = row0 + r;
            As[kk][r] = (gr < N) ? A[(long)gr * K + k0 + kk] : 0.f;
        }
        #pragma unroll
        for (int i = tid; i < 32 * 64; i += 256) {
            int kk = i >> 6, c = i & 63;
            int gc = col0 + c;
            Bs[kk][c] = (gc < M) ? B[(long)(k0 + kk) * M + gc] : 0.f;
        }
        __syncthreads();
        #pragma unroll
        for (int kk = 0; kk < 32; ++kk) {
            float a[4], b[4];
            #pragma unroll
            for (int i = 0; i < 4; ++i) a[i] = As[kk][ty * 4 + i];
            #pragma unroll
            for (int j = 0; j < 4; ++j) b[j] = Bs[kk][tx * 4 + j];
            #pragma unroll
            for (int i = 0; i < 4; ++i)
                #pragma unroll
                for (int j = 0; j < 4; ++j)
                    acc[i][j] += a[i] * b[j];
        }
        __syncthreads();
    }
    #pragma unroll
    for (int i = 0; i < 4; ++i) {
        int r = row0 + ty * 4 + i;
        if (r >= N) continue;
        #pragma unroll
        for (int j = 0; j < 4; ++j) {
            int c = col0 + tx * 4 + j;
            if (c < M) C[(long)r * M + c] = acc[i][j];
        }
    }
}

// ---------------- el/er projections ----------------
__global__ void attn_proj(const float* __restrict__ feat,
                          const float* __restrict__ al, const float* __restrict__ ar,
                          float* __restrict__ el, float* __restrict__ er,
                          int n, int H, int D) {
    int i = blockIdx.x * blockDim.x + threadIdx.x;
    if (i >= n * H) return;
    int h = i % H;
    const float* f = feat + (long)i * D;
    const float* a = al + h * D;
    const float* b = ar + h * D;
    float sl = 0.f, sr = 0.f;
    for (int d = 0; d < D; ++d) { float v = f[d]; sl += v * a[d]; sr += v * b[d]; }
    el[i] = sl;
    er[i] = sr;
}

// ---------------- edge scores e = leaky_relu(el[src]+er[dst]) ----------------
__global__ void edge_e(const float* __restrict__ el, const float* __restrict__ er,
                       const int* __restrict__ src, const int* __restrict__ dst,
                       float* __restrict__ e_out, int E, int H) {
    int e = blockIdx.x * blockDim.x + threadIdx.x;
    if (e >= E) return;
    int s = src[e], d = dst[e];
    for (int h = 0; h < H; ++h) {
        float v = el[s * H + h] + er[d * H + h];
        e_out[e * H + h] = (v >= 0.f) ? v : 0.2f * v;
    }
}

// ---------------- node-centric softmax + aggregation, one wave per node ----------------
template <int H, int D, int NELU, bool HAS_RES>
__global__ __launch_bounds__(256) void node_agg(
    const float* __restrict__ feat, const float* __restrict__ e_arr,
    const int* __restrict__ offs, const int* __restrict__ eidx,
    const int* __restrict__ src, const float* __restrict__ res,
    float* __restrict__ out, int n) {
    constexpr int HD = H * D;
    constexpr int F = (HD + 63) / 64;
    const int node = (int)((blockIdx.x * blockDim.x + threadIdx.x) >> 6);
    const int lane = threadIdx.x & 63;
    if (node >= n) return;
    const int beg = offs[node], end = offs[node + 1];

    // phase 1: per-head max over incoming edges
    float m[H];
    #pragma unroll
    for (int h = 0; h < H; ++h) m[h] = -INFINITY;
    for (int i = beg + lane; i < end; i += 64) {
        const int e = eidx[i];
        #pragma unroll
        for (int h = 0; h < H; ++h) m[h] = fmaxf(m[h], e_arr[e * H + h]);
    }
    #pragma unroll
    for (int off = 32; off > 0; off >>= 1)
        #pragma unroll
        for (int h = 0; h < H; ++h) m[h] = fmaxf(m[h], __shfl_xor(m[h], off));

    // phase 2: per-head sum of exp
    float s[H];
    #pragma unroll
    for (int h = 0; h < H; ++h) s[h] = 0.f;
    for (int i = beg + lane; i < end; i += 64) {
        const int e = eidx[i];
        #pragma unroll
        for (int h = 0; h < H; ++h) s[h] += expf(e_arr[e * H + h] - m[h]);
    }
    #pragma unroll
    for (int off = 32; off > 0; off >>= 1)
        #pragma unroll
        for (int h = 0; h < H; ++h) s[h] += __shfl_xor(s[h], off);

    float inv[H];
    #pragma unroll
    for (int h = 0; h < H; ++h) inv[h] = 1.f / fmaxf(s[h], 1e-9f);

    // phase 3: aggregate feat[src]*a
    float acc[F];
    #pragma unroll
    for (int f = 0; f < F; ++f) acc[f] = 0.f;
    for (int i = beg; i < end; ++i) {
        const int e = eidx[i];
        const int sn = src[e];
        #pragma unroll
        for (int f = 0; f < F; ++f) {
            const int fi = lane + 64 * f;
            if (HD % 64 == 0 || fi < HD) {
                const int h = fi / D;
                const float w = expf(e_arr[e * H + h] - m[h]) * inv[h];
                acc[f] += feat[(long)sn * HD + fi] * w;
            }
        }
    }

    // epilogue: residual + ELU^NELU
    #pragma unroll
    for (int f = 0; f < F; ++f) {
        const int fi = lane + 64 * f;
        if (HD % 64 == 0 || fi < HD) {
            float v = acc[f];
            if (HAS_RES) v += res[(long)node * HD + fi];
            #pragma unroll
            for (int t = 0; t < NELU; ++t) v = (v > 0.f) ? v : expm1f(v);
            out[(long)node * HD + fi] = v;
        }
    }
}

extern "C" void kernel_launch(void* const* d_in, const int* in_sizes, int n_in,
                              void* d_out, int out_size, void* d_ws, size_t ws_size,
                              hipStream_t stream) {
    const float* x     = (const float*)d_in[0];
    const float* W0    = (const float*)d_in[1];
    const float* al0   = (const float*)d_in[2];
    const float* ar0   = (const float*)d_in[3];
    const float* W1    = (const float*)d_in[4];
    const float* resW1 = (const float*)d_in[5];
    const float* al1   = (const float*)d_in[6];
    const float* ar1   = (const float*)d_in[7];
    const float* W2    = (const float*)d_in[8];
    const float* resW2 = (const float*)d_in[9];
    const float* al2   = (const float*)d_in[10];
    const float* ar2   = (const float*)d_in[11];
    const int*   src   = (const int*)d_in[12];
    const int*   dst   = (const int*)d_in[13];

    float* out    = (float*)d_out;
    float* logits = out;                 // [N, 47]
    float* e0     = out + (long)NN * NC; // [E, 4]
    float* e1     = e0 + (long)NE * NH;  // [E, 4]
    float* e2     = e1 + (long)NE * NH;  // [E, 1]

    char* p = (char*)d_ws;
    int* offs   = (int*)p; p += align256(sizeof(int) * (NN + 1));
    int* cursor = (int*)p; p += align256(sizeof(int) * NN);
    int* eidx   = (int*)p; p += align256(sizeof(int) * NE);
    float* el   = (float*)p; p += align256(sizeof(float) * NN * NH);
    float* er   = (float*)p; p += align256(sizeof(float) * NN * NH);
    float* feat = (float*)p; p += align256(sizeof(float) * (long)NN * 128);
    float* resb = (float*)p; p += align256(sizeof(float) * (long)NN * 128);
    float* hbuf = (float*)p; p += align256(sizeof(float) * (long)NN * 128);

    // ---- CSR by dst (rebuilt every call; same inputs -> same structure) ----
    hipMemsetAsync(cursor, 0, sizeof(int) * NN, stream);
    count_k<<<(NE + 255) / 256, 256, 0, stream>>>(dst, cursor, NE);
    scan_k<<<1, 1024, 0, stream>>>(cursor, offs, NN);
    hipMemcpyAsync(cursor, offs, sizeof(int) * NN, hipMemcpyDeviceToDevice, stream);
    fill_k<<<(NE + 255) / 256, 256, 0, stream>>>(dst, cursor, eidx, NE);

    const int gemmRows = (NN + 63) / 64;

    // ---- layer 0: x @ W0 -> feat[N,128]; no residual; ELU once after ----
    gemm64<<<dim3(gemmRows, 2), 256, 0, stream>>>(x, W0, feat, NN, FIN, NH * DH);
    attn_proj<<<(NN * NH + 255) / 256, 256, 0, stream>>>(feat, al0, ar0, el, er, NN, NH, DH);
    edge_e<<<(NE + 255) / 256, 256, 0, stream>>>(el, er, src, dst, e0, NE, NH);
    node_agg<NH, DH, 1, false><<<NN / 4, 256, 0, stream>>>(feat, e0, offs, eidx, src, nullptr, hbuf, NN);

    // ---- layer 1: h @ W1, h @ resW1; ELU twice (in-conv + outer) ----
    gemm64<<<dim3(gemmRows, 2), 256, 0, stream>>>(hbuf, W1, feat, NN, NH * DH, NH * DH);
    gemm64<<<dim3(gemmRows, 2), 256, 0, stream>>>(hbuf, resW1, resb, NN, NH * DH, NH * DH);
    attn_proj<<<(NN * NH + 255) / 256, 256, 0, stream>>>(feat, al1, ar1, el, er, NN, NH, DH);
    edge_e<<<(NE + 255) / 256, 256, 0, stream>>>(el, er, src, dst, e1, NE, NH);
    node_agg<NH, DH, 2, true><<<NN / 4, 256, 0, stream>>>(feat, e1, offs, eidx, src, resb, hbuf, NN);

    // ---- layer 2: h @ W2, h @ resW2 (M=47); no activation; logits ----
    gemm64<<<dim3(gemmRows, 1), 256, 0, stream>>>(hbuf, W2, feat, NN, NH * DH, NC);
    gemm64<<<dim3(gemmRows, 1), 256, 0, stream>>>(hbuf, resW2, resb, NN, NH * DH, NC);
    attn_proj<<<(NN + 255) / 256, 256, 0, stream>>>(feat, al2, ar2, el, er, NN, 1, NC);
    edge_e<<<(NE + 255) / 256, 256, 0, stream>>>(el, er, src, dst, e2, NE, 1);
    node_agg<1, NC, 0, true><<<NN / 4, 256, 0, stream>>>(feat, e2, offs, eidx, src, resb, logits, NN);
}

// Round 2
// 556.789 us; speedup vs baseline: 1.0218x; 1.0218x over previous
//
#include <hip/hip_runtime.h>
#include <hip/hip_bf16.h>
#include <math.h>

// Problem constants
#define NN 30000
#define NE 480000
#define FIN 256
#define DH 32
#define NH 4
#define NC 47

static inline size_t align256(size_t x) { return (x + 255) & ~(size_t)255; }

// ---------------- CSR build ----------------
__global__ void count_k(const int* __restrict__ dst, int* __restrict__ cnt, int E) {
    int e = blockIdx.x * blockDim.x + threadIdx.x;
    if (e < E) atomicAdd(&cnt[dst[e]], 1);
}

__global__ __launch_bounds__(1024) void scan_k(const int* __restrict__ cnt,
                                               int* __restrict__ offs, int n) {
    __shared__ int warp_sums[16];
    __shared__ int carry_s;
    const int lane = threadIdx.x & 63;
    const int wid = threadIdx.x >> 6;
    if (threadIdx.x == 0) carry_s = 0;
    __syncthreads();
    for (int base = 0; base < n; base += 1024) {
        int i = base + threadIdx.x;
        int v = (i < n) ? cnt[i] : 0;
        int x = v;
        #pragma unroll
        for (int off = 1; off < 64; off <<= 1) {
            int y = __shfl_up(x, off);
            if (lane >= off) x += y;
        }
        if (lane == 63) warp_sums[wid] = x;
        __syncthreads();
        if (wid == 0) {
            int ws = (lane < 16) ? warp_sums[lane] : 0;
            #pragma unroll
            for (int off = 1; off < 16; off <<= 1) {
                int y = __shfl_up(ws, off);
                if (lane >= off) ws += y;
            }
            if (lane < 16) warp_sums[lane] = ws;
        }
        __syncthreads();
        int wbase = (wid > 0) ? warp_sums[wid - 1] : 0;
        int incl = x + wbase + carry_s;
        if (i < n) offs[i] = incl - v;  // exclusive
        __syncthreads();
        if (threadIdx.x == 1023) carry_s = incl;
        __syncthreads();
    }
    if (threadIdx.x == 0) offs[n] = carry_s;
}

__global__ void fill_k(const int* __restrict__ dst, int* __restrict__ cursor,
                       int* __restrict__ eidx, int E) {
    int e = blockIdx.x * blockDim.x + threadIdx.x;
    if (e < E) {
        int p = atomicAdd(&cursor[dst[e]], 1);
        eidx[p] = e;
    }
}

// ---- f32 GEMM: C[N,M] = A[N,K] @ B[K,M], 64x64 tile; optional bf16 copy ----
__global__ __launch_bounds__(256) void gemm64(const float* __restrict__ A,
                                              const float* __restrict__ B,
                                              float* __restrict__ C,
                                              __hip_bfloat16* __restrict__ Cb,
                                              int N, int K, int M) {
    __shared__ float As[32][68];
    __shared__ float Bs[32][68];
    const int tid = threadIdx.x;
    const int tx = tid & 15;   // col group (4 cols)
    const int ty = tid >> 4;   // row group (4 rows)
    const int row0 = blockIdx.x * 64;
    const int col0 = blockIdx.y * 64;
    float acc[4][4] = {};
    for (int k0 = 0; k0 < K; k0 += 32) {
        #pragma unroll
        for (int i = tid; i < 64 * 32; i += 256) {
            int r = i >> 5, kk = i & 31;
            int gr = row0 + r;
            As[kk][r] = (gr < N) ? A[(long)gr * K + k0 + kk] : 0.f;
        }
        #pragma unroll
        for (int i = tid; i < 32 * 64; i += 256) {
            int kk = i >> 6, c = i & 63;
            int gc = col0 + c;
            Bs[kk][c] = (gc < M) ? B[(long)(k0 + kk) * M + gc] : 0.f;
        }
        __syncthreads();
        #pragma unroll
        for (int kk = 0; kk < 32; ++kk) {
            float a[4], b[4];
            #pragma unroll
            for (int i = 0; i < 4; ++i) a[i] = As[kk][ty * 4 + i];
            #pragma unroll
            for (int j = 0; j < 4; ++j) b[j] = Bs[kk][tx * 4 + j];
            #pragma unroll
            for (int i = 0; i < 4; ++i)
                #pragma unroll
                for (int j = 0; j < 4; ++j)
                    acc[i][j] += a[i] * b[j];
        }
        __syncthreads();
    }
    #pragma unroll
    for (int i = 0; i < 4; ++i) {
        int r = row0 + ty * 4 + i;
        if (r >= N) continue;
        #pragma unroll
        for (int j = 0; j < 4; ++j) {
            int c = col0 + tx * 4 + j;
            if (c < M) {
                C[(long)r * M + c] = acc[i][j];
                if (Cb) Cb[(long)r * M + c] = __float2bfloat16(acc[i][j]);
            }
        }
    }
}

// ---------------- el/er projections ----------------
__global__ void attn_proj(const float* __restrict__ feat,
                          const float* __restrict__ al, const float* __restrict__ ar,
                          float* __restrict__ el, float* __restrict__ er,
                          int n, int H, int D) {
    int i = blockIdx.x * blockDim.x + threadIdx.x;
    if (i >= n * H) return;
    int h = i % H;
    const float* f = feat + (long)i * D;
    const float* a = al + h * D;
    const float* b = ar + h * D;
    float sl = 0.f, sr = 0.f;
    for (int d = 0; d < D; ++d) { float v = f[d]; sl += v * a[d]; sr += v * b[d]; }
    el[i] = sl;
    er[i] = sr;
}

// ---------------- edge scores e = leaky_relu(el[src]+er[dst]) ----------------
template <int H>
__global__ void edge_e(const float* __restrict__ el, const float* __restrict__ er,
                       const int* __restrict__ src, const int* __restrict__ dst,
                       float* __restrict__ e_out, int E) {
    int e = blockIdx.x * blockDim.x + threadIdx.x;
    if (e >= E) return;
    int s = src[e], d = dst[e];
    if constexpr (H == 4) {
        float4 a = *reinterpret_cast<const float4*>(el + s * 4);
        float4 b = *reinterpret_cast<const float4*>(er + d * 4);
        float4 v;
        v.x = a.x + b.x; v.y = a.y + b.y; v.z = a.z + b.z; v.w = a.w + b.w;
        v.x = (v.x >= 0.f) ? v.x : 0.2f * v.x;
        v.y = (v.y >= 0.f) ? v.y : 0.2f * v.y;
        v.z = (v.z >= 0.f) ? v.z : 0.2f * v.z;
        v.w = (v.w >= 0.f) ? v.w : 0.2f * v.w;
        *reinterpret_cast<float4*>(e_out + e * 4) = v;
    } else {
        float v = el[s] + er[d];
        e_out[e] = (v >= 0.f) ? v : 0.2f * v;
    }
}

// ---- node-centric ONLINE softmax + aggregation (single edge pass), one wave/node ----
template <int H, int D, int NELU, bool HAS_RES>
__global__ __launch_bounds__(256) void node_agg(
    const __hip_bfloat16* __restrict__ featb, const float* __restrict__ e_arr,
    const int* __restrict__ offs, const int* __restrict__ eidx,
    const int* __restrict__ src, const float* __restrict__ res,
    float* __restrict__ out, int n) {
    constexpr int HD = H * D;
    const int node = (int)((blockIdx.x * blockDim.x + threadIdx.x) >> 6);
    const int lane = threadIdx.x & 63;
    if (node >= n) return;
    const int beg = offs[node], end = offs[node + 1];

    if constexpr (HD == 128) {
        const int fi = lane * 2;       // two consecutive features, same head
        const int h = fi / D;
        float m = -INFINITY, s = 0.f, acc0 = 0.f, acc1 = 0.f;
        for (int i = beg; i < end; ++i) {
            const int e = eidx[i];
            const int sn = src[e];
            const float ev = e_arr[e * H + h];
            if (ev > m) {
                const float r = __expf(m - ev);
                s *= r; acc0 *= r; acc1 *= r; m = ev;
            }
            const float w = __expf(ev - m);
            const __hip_bfloat162 f2 = *reinterpret_cast<const __hip_bfloat162*>(
                featb + (long)sn * HD + fi);
            s += w;
            acc0 += w * __bfloat162float(f2.x);
            acc1 += w * __bfloat162float(f2.y);
        }
        const float invs = 1.f / fmaxf(s, 1e-9f);
        float v0 = acc0 * invs, v1 = acc1 * invs;
        if constexpr (HAS_RES) {
            const float2 rr = *reinterpret_cast<const float2*>(res + (long)node * HD + fi);
            v0 += rr.x; v1 += rr.y;
        }
        #pragma unroll
        for (int t = 0; t < NELU; ++t) {
            v0 = (v0 > 0.f) ? v0 : expm1f(v0);
            v1 = (v1 > 0.f) ? v1 : expm1f(v1);
        }
        float2 o; o.x = v0; o.y = v1;
        *reinterpret_cast<float2*>(out + (long)node * HD + fi) = o;
    } else {
        // H == 1 (final layer, HD = 47)
        const bool active = lane < HD;
        float m = -INFINITY, s = 0.f, acc = 0.f;
        for (int i = beg; i < end; ++i) {
            const int e = eidx[i];
            const int sn = src[e];
            const float ev = e_arr[e];
            if (ev > m) {
                const float r = __expf(m - ev);
                s *= r; acc *= r; m = ev;
            }
            const float w = __expf(ev - m);
            s += w;
            if (active) acc += w * __bfloat162float(featb[(long)sn * HD + lane]);
        }
        if (active) {
            float v = acc / fmaxf(s, 1e-9f);
            if constexpr (HAS_RES) v += res[(long)node * HD + lane];
            #pragma unroll
            for (int t = 0; t < NELU; ++t) v = (v > 0.f) ? v : expm1f(v);
            out[(long)node * HD + lane] = v;
        }
    }
}

extern "C" void kernel_launch(void* const* d_in, const int* in_sizes, int n_in,
                              void* d_out, int out_size, void* d_ws, size_t ws_size,
                              hipStream_t stream) {
    const float* x     = (const float*)d_in[0];
    const float* W0    = (const float*)d_in[1];
    const float* al0   = (const float*)d_in[2];
    const float* ar0   = (const float*)d_in[3];
    const float* W1    = (const float*)d_in[4];
    const float* resW1 = (const float*)d_in[5];
    const float* al1   = (const float*)d_in[6];
    const float* ar1   = (const float*)d_in[7];
    const float* W2    = (const float*)d_in[8];
    const float* resW2 = (const float*)d_in[9];
    const float* al2   = (const float*)d_in[10];
    const float* ar2   = (const float*)d_in[11];
    const int*   src   = (const int*)d_in[12];
    const int*   dst   = (const int*)d_in[13];

    float* out    = (float*)d_out;
    float* logits = out;                 // [N, 47]
    float* e0     = out + (long)NN * NC; // [E, 4]
    float* e1     = e0 + (long)NE * NH;  // [E, 4]
    float* e2     = e1 + (long)NE * NH;  // [E, 1]

    char* p = (char*)d_ws;
    int* offs   = (int*)p; p += align256(sizeof(int) * (NN + 1));
    int* cursor = (int*)p; p += align256(sizeof(int) * NN);
    int* eidx   = (int*)p; p += align256(sizeof(int) * NE);
    float* el   = (float*)p; p += align256(sizeof(float) * NN * NH);
    float* er   = (float*)p; p += align256(sizeof(float) * NN * NH);
    float* feat = (float*)p; p += align256(sizeof(float) * (long)NN * 128);
    float* resb = (float*)p; p += align256(sizeof(float) * (long)NN * 128);
    float* hbuf = (float*)p; p += align256(sizeof(float) * (long)NN * 128);
    __hip_bfloat16* featb = (__hip_bfloat16*)p; p += align256(sizeof(__hip_bfloat16) * (long)NN * 128);

    // ---- CSR by dst (rebuilt every call; deterministic structure) ----
    hipMemsetAsync(cursor, 0, sizeof(int) * NN, stream);
    count_k<<<(NE + 255) / 256, 256, 0, stream>>>(dst, cursor, NE);
    scan_k<<<1, 1024, 0, stream>>>(cursor, offs, NN);
    hipMemcpyAsync(cursor, offs, sizeof(int) * NN, hipMemcpyDeviceToDevice, stream);
    fill_k<<<(NE + 255) / 256, 256, 0, stream>>>(dst, cursor, eidx, NE);

    const int gemmRows = (NN + 63) / 64;

    // ---- layer 0: x @ W0 -> feat[N,128] (+bf16 copy); ELU once after ----
    gemm64<<<dim3(gemmRows, 2), 256, 0, stream>>>(x, W0, feat, featb, NN, FIN, NH * DH);
    attn_proj<<<(NN * NH + 255) / 256, 256, 0, stream>>>(feat, al0, ar0, el, er, NN, NH, DH);
    edge_e<NH><<<(NE + 255) / 256, 256, 0, stream>>>(el, er, src, dst, e0, NE);
    node_agg<NH, DH, 1, false><<<NN / 4, 256, 0, stream>>>(featb, e0, offs, eidx, src, nullptr, hbuf, NN);

    // ---- layer 1: h @ W1 (+bf16), h @ resW1; ELU twice ----
    gemm64<<<dim3(gemmRows, 2), 256, 0, stream>>>(hbuf, W1, feat, featb, NN, NH * DH, NH * DH);
    gemm64<<<dim3(gemmRows, 2), 256, 0, stream>>>(hbuf, resW1, resb, nullptr, NN, NH * DH, NH * DH);
    attn_proj<<<(NN * NH + 255) / 256, 256, 0, stream>>>(feat, al1, ar1, el, er, NN, NH, DH);
    edge_e<NH><<<(NE + 255) / 256, 256, 0, stream>>>(el, er, src, dst, e1, NE);
    node_agg<NH, DH, 2, true><<<NN / 4, 256, 0, stream>>>(featb, e1, offs, eidx, src, resb, hbuf, NN);

    // ---- final layer: h @ W2 (+bf16), h @ resW2 (M=47); logits ----
    gemm64<<<dim3(gemmRows, 1), 256, 0, stream>>>(hbuf, W2, feat, featb, NN, NH * DH, NC);
    gemm64<<<dim3(gemmRows, 1), 256, 0, stream>>>(hbuf, resW2, resb, nullptr, NN, NH * DH, NC);
    attn_proj<<<(NN + 255) / 256, 256, 0, stream>>>(feat, al2, ar2, el, er, NN, 1, NC);
    edge_e<1><<<(NE + 255) / 256, 256, 0, stream>>>(el, er, src, dst, e2, NE);
    node_agg<1, NC, 0, true><<<NN / 4, 256, 0, stream>>>(featb, e2, offs, eidx, src, resb, logits, NN);
}

// Round 3
// 382.933 us; speedup vs baseline: 1.4857x; 1.4540x over previous
//
#include <hip/hip_runtime.h>
#include <hip/hip_bf16.h>
#include <math.h>

// Problem constants
#define NN 30000
#define NE 480000
#define FIN 256
#define DH 32
#define NH 4
#define NC 47

static inline size_t align256(size_t x) { return (x + 255) & ~(size_t)255; }

// ---------------- CSR build ----------------
__global__ void count_k(const int* __restrict__ dst, int* __restrict__ cnt, int E) {
    int e = blockIdx.x * blockDim.x + threadIdx.x;
    if (e < E) atomicAdd(&cnt[dst[e]], 1);
}

__global__ __launch_bounds__(1024) void scan_k(const int* __restrict__ cnt,
                                               int* __restrict__ offs, int n) {
    __shared__ int warp_sums[16];
    __shared__ int carry_s;
    const int lane = threadIdx.x & 63;
    const int wid = threadIdx.x >> 6;
    if (threadIdx.x == 0) carry_s = 0;
    __syncthreads();
    for (int base = 0; base < n; base += 1024) {
        int i = base + threadIdx.x;
        int v = (i < n) ? cnt[i] : 0;
        int x = v;
        #pragma unroll
        for (int off = 1; off < 64; off <<= 1) {
            int y = __shfl_up(x, off);
            if (lane >= off) x += y;
        }
        if (lane == 63) warp_sums[wid] = x;
        __syncthreads();
        if (wid == 0) {
            int ws = (lane < 16) ? warp_sums[lane] : 0;
            #pragma unroll
            for (int off = 1; off < 16; off <<= 1) {
                int y = __shfl_up(ws, off);
                if (lane >= off) ws += y;
            }
            if (lane < 16) warp_sums[lane] = ws;
        }
        __syncthreads();
        int wbase = (wid > 0) ? warp_sums[wid - 1] : 0;
        int incl = x + wbase + carry_s;
        if (i < n) offs[i] = incl - v;  // exclusive
        __syncthreads();
        if (threadIdx.x == 1023) carry_s = incl;
        __syncthreads();
    }
    if (threadIdx.x == 0) offs[n] = carry_s;
}

// writes pos[e] (CSR slot of edge e) and srcs[slot] (src id in CSR order)
__global__ void fill_k(const int* __restrict__ dst, const int* __restrict__ src,
                       int* __restrict__ cursor, int* __restrict__ pos,
                       int* __restrict__ srcs, int E) {
    int e = blockIdx.x * blockDim.x + threadIdx.x;
    if (e < E) {
        int p = atomicAdd(&cursor[dst[e]], 1);
        pos[e] = p;
        srcs[p] = src[e];
    }
}

// ---- f32 GEMM: C[N,M] = A[N,K] @ B[K,M], 64x64 tile; optional bf16 copy ----
__global__ __launch_bounds__(256) void gemm64(const float* __restrict__ A,
                                              const float* __restrict__ B,
                                              float* __restrict__ C,
                                              __hip_bfloat16* __restrict__ Cb,
                                              int N, int K, int M) {
    __shared__ float As[32][72];   // stride 288B -> float4-aligned rows
    __shared__ float Bs[32][72];
    const int tid = threadIdx.x;
    const int tx = tid & 15;   // col group (4 cols)
    const int ty = tid >> 4;   // row group (4 rows)
    const int row0 = blockIdx.x * 64;
    const int col0 = blockIdx.y * 64;
    float acc[4][4] = {};
    for (int k0 = 0; k0 < K; k0 += 32) {
        #pragma unroll
        for (int i = tid; i < 64 * 32; i += 256) {
            int r = i >> 5, kk = i & 31;
            int gr = row0 + r;
            As[kk][r] = (gr < N) ? A[(long)gr * K + k0 + kk] : 0.f;
        }
        #pragma unroll
        for (int i = tid; i < 32 * 64; i += 256) {
            int kk = i >> 6, c = i & 63;
            int gc = col0 + c;
            Bs[kk][c] = (gc < M) ? B[(long)(k0 + kk) * M + gc] : 0.f;
        }
        __syncthreads();
        #pragma unroll
        for (int kk = 0; kk < 32; ++kk) {
            const float4 a = *reinterpret_cast<const float4*>(&As[kk][ty * 4]);
            const float4 b = *reinterpret_cast<const float4*>(&Bs[kk][tx * 4]);
            acc[0][0] += a.x * b.x; acc[0][1] += a.x * b.y; acc[0][2] += a.x * b.z; acc[0][3] += a.x * b.w;
            acc[1][0] += a.y * b.x; acc[1][1] += a.y * b.y; acc[1][2] += a.y * b.z; acc[1][3] += a.y * b.w;
            acc[2][0] += a.z * b.x; acc[2][1] += a.z * b.y; acc[2][2] += a.z * b.z; acc[2][3] += a.z * b.w;
            acc[3][0] += a.w * b.x; acc[3][1] += a.w * b.y; acc[3][2] += a.w * b.z; acc[3][3] += a.w * b.w;
        }
        __syncthreads();
    }
    #pragma unroll
    for (int i = 0; i < 4; ++i) {
        int r = row0 + ty * 4 + i;
        if (r >= N) continue;
        #pragma unroll
        for (int j = 0; j < 4; ++j) {
            int c = col0 + tx * 4 + j;
            if (c < M) {
                C[(long)r * M + c] = acc[i][j];
                if (Cb) Cb[(long)r * M + c] = __float2bfloat16(acc[i][j]);
            }
        }
    }
}

// ---------------- el/er projections ----------------
template <int H, int D>
__global__ void attn_proj(const float* __restrict__ feat,
                          const float* __restrict__ al, const float* __restrict__ ar,
                          float* __restrict__ el, float* __restrict__ er, int n) {
    int i = blockIdx.x * blockDim.x + threadIdx.x;
    if (i >= n * H) return;
    int h = i % H;
    const float* f = feat + (long)i * D;
    const float* a = al + h * D;
    const float* b = ar + h * D;
    float sl = 0.f, sr = 0.f;
    if constexpr (D % 4 == 0) {
        #pragma unroll
        for (int d = 0; d < D / 4; ++d) {
            float4 v = *reinterpret_cast<const float4*>(f + d * 4);
            float4 av = *reinterpret_cast<const float4*>(a + d * 4);
            float4 bv = *reinterpret_cast<const float4*>(b + d * 4);
            sl += v.x * av.x + v.y * av.y + v.z * av.z + v.w * av.w;
            sr += v.x * bv.x + v.y * bv.y + v.z * bv.z + v.w * bv.w;
        }
    } else {
        for (int d = 0; d < D; ++d) { float v = f[d]; sl += v * a[d]; sr += v * b[d]; }
    }
    el[i] = sl;
    er[i] = sr;
}

// ---- edge scores e = leaky_relu(el[src]+er[dst]); dual write: edge order + CSR order ----
template <int H>
__global__ void edge_e(const float* __restrict__ el, const float* __restrict__ er,
                       const int* __restrict__ src, const int* __restrict__ dst,
                       const int* __restrict__ pos,
                       float* __restrict__ e_out, float* __restrict__ es, int E) {
    int e = blockIdx.x * blockDim.x + threadIdx.x;
    if (e >= E) return;
    int s = src[e], d = dst[e], p = pos[e];
    if constexpr (H == 4) {
        float4 a = *reinterpret_cast<const float4*>(el + s * 4);
        float4 b = *reinterpret_cast<const float4*>(er + d * 4);
        float4 v;
        v.x = a.x + b.x; v.y = a.y + b.y; v.z = a.z + b.z; v.w = a.w + b.w;
        v.x = (v.x >= 0.f) ? v.x : 0.2f * v.x;
        v.y = (v.y >= 0.f) ? v.y : 0.2f * v.y;
        v.z = (v.z >= 0.f) ? v.z : 0.2f * v.z;
        v.w = (v.w >= 0.f) ? v.w : 0.2f * v.w;
        *reinterpret_cast<float4*>(e_out + e * 4) = v;
        *reinterpret_cast<float4*>(es + p * 4) = v;
    } else {
        float v = el[s] + er[d];
        v = (v >= 0.f) ? v : 0.2f * v;
        e_out[e] = v;
        es[p] = v;
    }
}

// ---- node-centric softmax + aggregation, one wave/node, H=4 D=32 (HD=128) ----
template <int NELU, bool HAS_RES>
__global__ __launch_bounds__(256) void node_agg4(
    const __hip_bfloat16* __restrict__ featb, const float4* __restrict__ es4,
    const int* __restrict__ offs, const int* __restrict__ srcs,
    const float* __restrict__ res, float* __restrict__ out, int n) {
    const int node = (int)((blockIdx.x * blockDim.x + threadIdx.x) >> 6);
    const int lane = threadIdx.x & 63;
    if (node >= n) return;
    const int beg = offs[node], end = offs[node + 1];

    // phase 1: per-head max (lane-parallel, coalesced reads of CSR-ordered scores)
    float4 m4 = make_float4(-INFINITY, -INFINITY, -INFINITY, -INFINITY);
    for (int i = beg + lane; i < end; i += 64) {
        float4 v = es4[i];
        m4.x = fmaxf(m4.x, v.x); m4.y = fmaxf(m4.y, v.y);
        m4.z = fmaxf(m4.z, v.z); m4.w = fmaxf(m4.w, v.w);
    }
    #pragma unroll
    for (int off = 32; off > 0; off >>= 1) {
        m4.x = fmaxf(m4.x, __shfl_xor(m4.x, off));
        m4.y = fmaxf(m4.y, __shfl_xor(m4.y, off));
        m4.z = fmaxf(m4.z, __shfl_xor(m4.z, off));
        m4.w = fmaxf(m4.w, __shfl_xor(m4.w, off));
    }
    // phase 2: per-head sum of exp
    float4 s4 = make_float4(0.f, 0.f, 0.f, 0.f);
    for (int i = beg + lane; i < end; i += 64) {
        float4 v = es4[i];
        s4.x += __expf(v.x - m4.x); s4.y += __expf(v.y - m4.y);
        s4.z += __expf(v.z - m4.z); s4.w += __expf(v.w - m4.w);
    }
    #pragma unroll
    for (int off = 32; off > 0; off >>= 1) {
        s4.x += __shfl_xor(s4.x, off);
        s4.y += __shfl_xor(s4.y, off);
        s4.z += __shfl_xor(s4.z, off);
        s4.w += __shfl_xor(s4.w, off);
    }

    const int fi = lane * 2;           // two consecutive features, same head
    const int h = lane >> 4;           // fi / 32
    const float m  = (h == 0) ? m4.x : (h == 1) ? m4.y : (h == 2) ? m4.z : m4.w;
    const float sv = (h == 0) ? s4.x : (h == 1) ? s4.y : (h == 2) ? s4.z : s4.w;
    const float inv = 1.f / fmaxf(sv, 1e-9f);

    // phase 3: aggregation — independent iterations, unrolled x4
    const float* esf = (const float*)es4;
    float acc0 = 0.f, acc1 = 0.f;
    int i = beg;
    for (; i + 4 <= end; i += 4) {
        const int sn0 = srcs[i], sn1 = srcs[i + 1], sn2 = srcs[i + 2], sn3 = srcs[i + 3];
        const float ev0 = esf[(i + 0) * 4 + h];
        const float ev1 = esf[(i + 1) * 4 + h];
        const float ev2 = esf[(i + 2) * 4 + h];
        const float ev3 = esf[(i + 3) * 4 + h];
        const __hip_bfloat162 f0 = *reinterpret_cast<const __hip_bfloat162*>(featb + (long)sn0 * 128 + fi);
        const __hip_bfloat162 f1 = *reinterpret_cast<const __hip_bfloat162*>(featb + (long)sn1 * 128 + fi);
        const __hip_bfloat162 f2 = *reinterpret_cast<const __hip_bfloat162*>(featb + (long)sn2 * 128 + fi);
        const __hip_bfloat162 f3 = *reinterpret_cast<const __hip_bfloat162*>(featb + (long)sn3 * 128 + fi);
        const float w0 = __expf(ev0 - m), w1 = __expf(ev1 - m);
        const float w2 = __expf(ev2 - m), w3 = __expf(ev3 - m);
        acc0 += w0 * __bfloat162float(f0.x); acc1 += w0 * __bfloat162float(f0.y);
        acc0 += w1 * __bfloat162float(f1.x); acc1 += w1 * __bfloat162float(f1.y);
        acc0 += w2 * __bfloat162float(f2.x); acc1 += w2 * __bfloat162float(f2.y);
        acc0 += w3 * __bfloat162float(f3.x); acc1 += w3 * __bfloat162float(f3.y);
    }
    for (; i < end; ++i) {
        const int sn = srcs[i];
        const float w = __expf(esf[i * 4 + h] - m);
        const __hip_bfloat162 f2 = *reinterpret_cast<const __hip_bfloat162*>(featb + (long)sn * 128 + fi);
        acc0 += w * __bfloat162float(f2.x);
        acc1 += w * __bfloat162float(f2.y);
    }

    float v0 = acc0 * inv, v1 = acc1 * inv;
    if constexpr (HAS_RES) {
        const float2 rr = *reinterpret_cast<const float2*>(res + (long)node * 128 + fi);
        v0 += rr.x; v1 += rr.y;
    }
    #pragma unroll
    for (int t = 0; t < NELU; ++t) {
        v0 = (v0 > 0.f) ? v0 : expm1f(v0);
        v1 = (v1 > 0.f) ? v1 : expm1f(v1);
    }
    float2 o; o.x = v0; o.y = v1;
    *reinterpret_cast<float2*>(out + (long)node * 128 + fi) = o;
}

// ---- node-centric softmax + aggregation, H=1, HD=47 (final layer) ----
__global__ __launch_bounds__(256) void node_agg1(
    const __hip_bfloat16* __restrict__ featb, const float* __restrict__ es1,
    const int* __restrict__ offs, const int* __restrict__ srcs,
    const float* __restrict__ res, float* __restrict__ out, int n) {
    const int node = (int)((blockIdx.x * blockDim.x + threadIdx.x) >> 6);
    const int lane = threadIdx.x & 63;
    if (node >= n) return;
    const int beg = offs[node], end = offs[node + 1];

    float m = -INFINITY;
    for (int i = beg + lane; i < end; i += 64) m = fmaxf(m, es1[i]);
    #pragma unroll
    for (int off = 32; off > 0; off >>= 1) m = fmaxf(m, __shfl_xor(m, off));
    float s = 0.f;
    for (int i = beg + lane; i < end; i += 64) s += __expf(es1[i] - m);
    #pragma unroll
    for (int off = 32; off > 0; off >>= 1) s += __shfl_xor(s, off);
    const float inv = 1.f / fmaxf(s, 1e-9f);

    const bool active = lane < NC;
    float acc = 0.f;
    int i = beg;
    for (; i + 4 <= end; i += 4) {
        const int sn0 = srcs[i], sn1 = srcs[i + 1], sn2 = srcs[i + 2], sn3 = srcs[i + 3];
        const float w0 = __expf(es1[i + 0] - m);
        const float w1 = __expf(es1[i + 1] - m);
        const float w2 = __expf(es1[i + 2] - m);
        const float w3 = __expf(es1[i + 3] - m);
        if (active) {
            acc += w0 * __bfloat162float(featb[(long)sn0 * NC + lane]);
            acc += w1 * __bfloat162float(featb[(long)sn1 * NC + lane]);
            acc += w2 * __bfloat162float(featb[(long)sn2 * NC + lane]);
            acc += w3 * __bfloat162float(featb[(long)sn3 * NC + lane]);
        }
    }
    for (; i < end; ++i) {
        const float w = __expf(es1[i] - m);
        if (active) acc += w * __bfloat162float(featb[(long)srcs[i] * NC + lane]);
    }
    if (active) {
        float v = acc * inv + res[(long)node * NC + lane];
        out[(long)node * NC + lane] = v;
    }
}

extern "C" void kernel_launch(void* const* d_in, const int* in_sizes, int n_in,
                              void* d_out, int out_size, void* d_ws, size_t ws_size,
                              hipStream_t stream) {
    const float* x     = (const float*)d_in[0];
    const float* W0    = (const float*)d_in[1];
    const float* al0   = (const float*)d_in[2];
    const float* ar0   = (const float*)d_in[3];
    const float* W1    = (const float*)d_in[4];
    const float* resW1 = (const float*)d_in[5];
    const float* al1   = (const float*)d_in[6];
    const float* ar1   = (const float*)d_in[7];
    const float* W2    = (const float*)d_in[8];
    const float* resW2 = (const float*)d_in[9];
    const float* al2   = (const float*)d_in[10];
    const float* ar2   = (const float*)d_in[11];
    const int*   src   = (const int*)d_in[12];
    const int*   dst   = (const int*)d_in[13];

    float* out    = (float*)d_out;
    float* logits = out;                 // [N, 47]
    float* e0     = out + (long)NN * NC; // [E, 4]
    float* e1     = e0 + (long)NE * NH;  // [E, 4]
    float* e2     = e1 + (long)NE * NH;  // [E, 1]

    char* p = (char*)d_ws;
    int* offs   = (int*)p; p += align256(sizeof(int) * (NN + 1));
    int* cursor = (int*)p; p += align256(sizeof(int) * NN);
    int* pos    = (int*)p; p += align256(sizeof(int) * NE);
    int* srcs   = (int*)p; p += align256(sizeof(int) * NE);
    float* el   = (float*)p; p += align256(sizeof(float) * NN * NH);
    float* er   = (float*)p; p += align256(sizeof(float) * NN * NH);
    float* feat = (float*)p; p += align256(sizeof(float) * (long)NN * 128);
    float* resb = (float*)p; p += align256(sizeof(float) * (long)NN * 128);
    float* hbuf = (float*)p; p += align256(sizeof(float) * (long)NN * 128);
    __hip_bfloat16* featb = (__hip_bfloat16*)p; p += align256(sizeof(__hip_bfloat16) * (long)NN * 128);
    // CSR-ordered scores alias the f32 feat buffer: feat is only live between
    // gemm and attn_proj; es is only live between edge_e and node_agg. Disjoint.
    float* es = feat;   // [E,4] f32 (7.68 MB) fits in feat's 15.36 MB region

    // ---- CSR by dst (rebuilt every call; deterministic structure) ----
    hipMemsetAsync(cursor, 0, sizeof(int) * NN, stream);
    count_k<<<(NE + 255) / 256, 256, 0, stream>>>(dst, cursor, NE);
    scan_k<<<1, 1024, 0, stream>>>(cursor, offs, NN);
    hipMemcpyAsync(cursor, offs, sizeof(int) * NN, hipMemcpyDeviceToDevice, stream);
    fill_k<<<(NE + 255) / 256, 256, 0, stream>>>(dst, src, cursor, pos, srcs, NE);

    const int gemmRows = (NN + 63) / 64;
    const int edgeBlocks = (NE + 255) / 256;
    const int nodeBlocks = NN / 4;   // one wave per node, 4 waves/block

    // ---- layer 0: x @ W0 -> feat[N,128] (+bf16); ELU once after ----
    gemm64<<<dim3(gemmRows, 2), 256, 0, stream>>>(x, W0, feat, featb, NN, FIN, NH * DH);
    attn_proj<NH, DH><<<(NN * NH + 255) / 256, 256, 0, stream>>>(feat, al0, ar0, el, er, NN);
    edge_e<NH><<<edgeBlocks, 256, 0, stream>>>(el, er, src, dst, pos, e0, es, NE);
    node_agg4<1, false><<<nodeBlocks, 256, 0, stream>>>(featb, (const float4*)es, offs, srcs, nullptr, hbuf, NN);

    // ---- layer 1: h @ W1 (+bf16), h @ resW1; ELU twice ----
    gemm64<<<dim3(gemmRows, 2), 256, 0, stream>>>(hbuf, W1, feat, featb, NN, NH * DH, NH * DH);
    gemm64<<<dim3(gemmRows, 2), 256, 0, stream>>>(hbuf, resW1, resb, nullptr, NN, NH * DH, NH * DH);
    attn_proj<NH, DH><<<(NN * NH + 255) / 256, 256, 0, stream>>>(feat, al1, ar1, el, er, NN);
    edge_e<NH><<<edgeBlocks, 256, 0, stream>>>(el, er, src, dst, pos, e1, es, NE);
    node_agg4<2, true><<<nodeBlocks, 256, 0, stream>>>(featb, (const float4*)es, offs, srcs, resb, hbuf, NN);

    // ---- final layer: h @ W2 (+bf16), h @ resW2 (M=47); logits ----
    gemm64<<<dim3(gemmRows, 1), 256, 0, stream>>>(hbuf, W2, feat, featb, NN, NH * DH, NC);
    gemm64<<<dim3(gemmRows, 1), 256, 0, stream>>>(hbuf, resW2, resb, nullptr, NN, NH * DH, NC);
    attn_proj<1, NC><<<(NN + 255) / 256, 256, 0, stream>>>(feat, al2, ar2, el, er, NN);
    edge_e<1><<<edgeBlocks, 256, 0, stream>>>(el, er, src, dst, pos, e2, es, NE);
    node_agg1<<<nodeBlocks, 256, 0, stream>>>(featb, es, offs, srcs, resb, logits, NN);
}

// Round 4
// 271.825 us; speedup vs baseline: 2.0929x; 1.4087x over previous
//
#include <hip/hip_runtime.h>
#include <hip/hip_bf16.h>
#include <math.h>

// Problem constants
#define NN 30000
#define NE 480000
#define FIN 256
#define DH 32
#define NH 4
#define NC 47

typedef __attribute__((ext_vector_type(8))) short frag_ab;  // 8 bf16 (4 VGPR)
typedef __attribute__((ext_vector_type(4))) float f32x4;    // MFMA 16x16 accum
typedef __hip_bfloat16 bf16;

static inline size_t align256(size_t x) { return (x + 255) & ~(size_t)255; }

__device__ __forceinline__ short f2bf(float f) {
    union { float f; unsigned u; } c; c.f = f;
    unsigned r = (c.u + 0x7FFFu + ((c.u >> 16) & 1u)) >> 16;  // RNE
    return (short)r;
}

// ---------------- CSR build ----------------
__global__ void count_k(const int* __restrict__ dst, int* __restrict__ cnt, int E) {
    int e = blockIdx.x * blockDim.x + threadIdx.x;
    if (e < E) atomicAdd(&cnt[dst[e]], 1);
}

__global__ __launch_bounds__(1024) void scan_k(const int* __restrict__ cnt,
                                               int* __restrict__ offs, int n) {
    __shared__ int warp_sums[16];
    __shared__ int carry_s;
    const int lane = threadIdx.x & 63;
    const int wid = threadIdx.x >> 6;
    if (threadIdx.x == 0) carry_s = 0;
    __syncthreads();
    for (int base = 0; base < n; base += 1024) {
        int i = base + threadIdx.x;
        int v = (i < n) ? cnt[i] : 0;
        int x = v;
        #pragma unroll
        for (int off = 1; off < 64; off <<= 1) {
            int y = __shfl_up(x, off);
            if (lane >= off) x += y;
        }
        if (lane == 63) warp_sums[wid] = x;
        __syncthreads();
        if (wid == 0) {
            int ws = (lane < 16) ? warp_sums[lane] : 0;
            #pragma unroll
            for (int off = 1; off < 16; off <<= 1) {
                int y = __shfl_up(ws, off);
                if (lane >= off) ws += y;
            }
            if (lane < 16) warp_sums[lane] = ws;
        }
        __syncthreads();
        int wbase = (wid > 0) ? warp_sums[wid - 1] : 0;
        int incl = x + wbase + carry_s;
        if (i < n) offs[i] = incl - v;  // exclusive
        __syncthreads();
        if (threadIdx.x == 1023) carry_s = incl;
        __syncthreads();
    }
    if (threadIdx.x == 0) offs[n] = carry_s;
}

// writes pos[e] (CSR slot of edge e) and srcs[slot] (src id in CSR order)
__global__ void fill_k(const int* __restrict__ dst, const int* __restrict__ src,
                       int* __restrict__ cursor, int* __restrict__ pos,
                       int* __restrict__ srcs, int E) {
    int e = blockIdx.x * blockDim.x + threadIdx.x;
    if (e < E) {
        int p = atomicAdd(&cursor[dst[e]], 1);
        pos[e] = p;
        srcs[p] = src[e];
    }
}

// ---- weight prep: cast + transpose to bf16, Wt[m][k] = W[k][m], zero-pad m>=M ----
__global__ void prep_w_all(const float* __restrict__ W0, const float* __restrict__ W1,
                           const float* __restrict__ rW1, const float* __restrict__ W2,
                           const float* __restrict__ rW2,
                           bf16* __restrict__ W0t, bf16* __restrict__ W1t,
                           bf16* __restrict__ rW1t, bf16* __restrict__ W2t,
                           bf16* __restrict__ rW2t) {
    const float* W; bf16* Wt; int K, M, Mpad;
    switch (blockIdx.y) {
        case 0: W = W0;  Wt = W0t;  K = 256; M = 128; Mpad = 128; break;
        case 1: W = W1;  Wt = W1t;  K = 128; M = 128; Mpad = 128; break;
        case 2: W = rW1; Wt = rW1t; K = 128; M = 128; Mpad = 128; break;
        case 3: W = W2;  Wt = W2t;  K = 128; M = 47;  Mpad = 48;  break;
        default: W = rW2; Wt = rW2t; K = 128; M = 47; Mpad = 48;  break;
    }
    int i = blockIdx.x * 256 + threadIdx.x;
    if (i >= Mpad * K) return;
    int m = i / K, k = i - m * K;
    float v = (m < M) ? W[(long)k * M + m] : 0.f;
    Wt[i] = __float2bfloat16(v);
}

// ---- bf16 MFMA GEMM: C[N,M] = A[N,K] @ B[K,M]; optional dual B / bf16 C copy ----
// Block: 64 rows x NT*16 cols, 4 waves (wave w owns rows w*16..w*16+15).
// Bt layout: [NT*16][K] row-major bf16 (transposed, zero-padded weights).
template <bool A_F32, int NT, bool DUAL>
__global__ __launch_bounds__(256) void gemm_mfma(
    const void* __restrict__ Av, const bf16* __restrict__ B1t,
    const bf16* __restrict__ B2t,
    float* __restrict__ C1, bf16* __restrict__ C1b, float* __restrict__ C2,
    int N, int K, int M) {
    constexpr int LP = 56;  // 32 k + 24 pad: rows 112B (16B-aligned, <=2-way bank alias)
    __shared__ bf16 As[64][LP];
    __shared__ bf16 Bs1[NT * 16][LP];
    __shared__ bf16 Bs2[DUAL ? NT * 16 : 1][LP];

    const int tid = threadIdx.x;
    const int lane = tid & 63;
    const int wid = tid >> 6;
    const int row0 = blockIdx.x * 64;
    const int l15 = lane & 15;
    const int kq = lane >> 4;          // k-quarter 0..3

    f32x4 acc1[NT], acc2[DUAL ? NT : 1];
    #pragma unroll
    for (int t = 0; t < NT; ++t) acc1[t] = (f32x4){0.f, 0.f, 0.f, 0.f};
    if constexpr (DUAL) {
        #pragma unroll
        for (int t = 0; t < NT; ++t) acc2[t] = (f32x4){0.f, 0.f, 0.f, 0.f};
    }

    for (int k0 = 0; k0 < K; k0 += 32) {
        // stage A: 64 rows x 32 k (each thread: 8 contiguous k of one row)
        {
            const int r = tid >> 2, kk = (tid & 3) * 8;
            const int gr = row0 + r;
            if constexpr (A_F32) {
                const float* A = (const float*)Av;
                short tmp[8];
                if (gr < N) {
                    const float4 v0 = *(const float4*)&A[(long)gr * K + k0 + kk];
                    const float4 v1 = *(const float4*)&A[(long)gr * K + k0 + kk + 4];
                    tmp[0] = f2bf(v0.x); tmp[1] = f2bf(v0.y); tmp[2] = f2bf(v0.z); tmp[3] = f2bf(v0.w);
                    tmp[4] = f2bf(v1.x); tmp[5] = f2bf(v1.y); tmp[6] = f2bf(v1.z); tmp[7] = f2bf(v1.w);
                } else {
                    #pragma unroll
                    for (int j = 0; j < 8; ++j) tmp[j] = 0;
                }
                *(frag_ab*)&As[r][kk] = *(const frag_ab*)tmp;
            } else {
                const bf16* A = (const bf16*)Av;
                frag_ab v = {0, 0, 0, 0, 0, 0, 0, 0};
                if (gr < N) v = *(const frag_ab*)&A[(long)gr * K + k0 + kk];
                *(frag_ab*)&As[r][kk] = v;
            }
        }
        // stage B tiles: NT*16 cols x 32 k (coalesced rows of Wt)
        for (int i = tid; i < NT * 64; i += 256) {
            const int c = i >> 2, kk = (i & 3) * 8;
            *(frag_ab*)&Bs1[c][kk] = *(const frag_ab*)&B1t[(long)c * K + k0 + kk];
            if constexpr (DUAL)
                *(frag_ab*)&Bs2[c][kk] = *(const frag_ab*)&B2t[(long)c * K + k0 + kk];
        }
        __syncthreads();

        const frag_ab a = *(const frag_ab*)&As[wid * 16 + l15][kq * 8];
        #pragma unroll
        for (int t = 0; t < NT; ++t) {
            const frag_ab b = *(const frag_ab*)&Bs1[t * 16 + l15][kq * 8];
            acc1[t] = __builtin_amdgcn_mfma_f32_16x16x32_bf16(a, b, acc1[t], 0, 0, 0);
        }
        if constexpr (DUAL) {
            #pragma unroll
            for (int t = 0; t < NT; ++t) {
                const frag_ab b = *(const frag_ab*)&Bs2[t * 16 + l15][kq * 8];
                acc2[t] = __builtin_amdgcn_mfma_f32_16x16x32_bf16(a, b, acc2[t], 0, 0, 0);
            }
        }
        __syncthreads();
    }

    // epilogue: D row = (lane>>4)*4 + reg, col = lane&15 (m89-verified layout)
    const int r0 = row0 + wid * 16 + kq * 4;
    #pragma unroll
    for (int t = 0; t < NT; ++t) {
        const int c = t * 16 + l15;
        if (NT == 3 && c >= M) continue;
        #pragma unroll
        for (int reg = 0; reg < 4; ++reg) {
            const int r = r0 + reg;
            if (r < N) {
                const long o = (long)r * M + c;
                C1[o] = acc1[t][reg];
                if (C1b) C1b[o] = __float2bfloat16(acc1[t][reg]);
                if constexpr (DUAL) C2[o] = acc2[t][reg];
            }
        }
    }
}

// ---------------- el/er projections ----------------
template <int H, int D>
__global__ void attn_proj(const float* __restrict__ feat,
                          const float* __restrict__ al, const float* __restrict__ ar,
                          float* __restrict__ el, float* __restrict__ er, int n) {
    int i = blockIdx.x * blockDim.x + threadIdx.x;
    if (i >= n * H) return;
    int h = i % H;
    const float* f = feat + (long)i * D;
    const float* a = al + h * D;
    const float* b = ar + h * D;
    float sl = 0.f, sr = 0.f;
    if constexpr (D % 4 == 0) {
        #pragma unroll
        for (int d = 0; d < D / 4; ++d) {
            float4 v = *reinterpret_cast<const float4*>(f + d * 4);
            float4 av = *reinterpret_cast<const float4*>(a + d * 4);
            float4 bv = *reinterpret_cast<const float4*>(b + d * 4);
            sl += v.x * av.x + v.y * av.y + v.z * av.z + v.w * av.w;
            sr += v.x * bv.x + v.y * bv.y + v.z * bv.z + v.w * bv.w;
        }
    } else {
        for (int d = 0; d < D; ++d) { float v = f[d]; sl += v * a[d]; sr += v * b[d]; }
    }
    el[i] = sl;
    er[i] = sr;
}

// ---- edge scores e = leaky_relu(el[src]+er[dst]); dual write: edge order + CSR order ----
template <int H>
__global__ void edge_e(const float* __restrict__ el, const float* __restrict__ er,
                       const int* __restrict__ src, const int* __restrict__ dst,
                       const int* __restrict__ pos,
                       float* __restrict__ e_out, float* __restrict__ es, int E) {
    int e = blockIdx.x * blockDim.x + threadIdx.x;
    if (e >= E) return;
    int s = src[e], d = dst[e], p = pos[e];
    if constexpr (H == 4) {
        float4 a = *reinterpret_cast<const float4*>(el + s * 4);
        float4 b = *reinterpret_cast<const float4*>(er + d * 4);
        float4 v;
        v.x = a.x + b.x; v.y = a.y + b.y; v.z = a.z + b.z; v.w = a.w + b.w;
        v.x = (v.x >= 0.f) ? v.x : 0.2f * v.x;
        v.y = (v.y >= 0.f) ? v.y : 0.2f * v.y;
        v.z = (v.z >= 0.f) ? v.z : 0.2f * v.z;
        v.w = (v.w >= 0.f) ? v.w : 0.2f * v.w;
        *reinterpret_cast<float4*>(e_out + e * 4) = v;
        *reinterpret_cast<float4*>(es + p * 4) = v;
    } else {
        float v = el[s] + er[d];
        v = (v >= 0.f) ? v : 0.2f * v;
        e_out[e] = v;
        es[p] = v;
    }
}

// ---- node-centric softmax + aggregation, one wave/node, H=4 D=32 (HD=128) ----
// out is bf16 (next layer's GEMM A input); NELU applied before cast.
template <int NELU, bool HAS_RES>
__global__ __launch_bounds__(256) void node_agg4(
    const bf16* __restrict__ featb, const float4* __restrict__ es4,
    const int* __restrict__ offs, const int* __restrict__ srcs,
    const float* __restrict__ res, bf16* __restrict__ out, int n) {
    const int node = (int)((blockIdx.x * blockDim.x + threadIdx.x) >> 6);
    const int lane = threadIdx.x & 63;
    if (node >= n) return;
    const int beg = offs[node], end = offs[node + 1];

    // phase 1: per-head max (lane-parallel, coalesced CSR-ordered scores)
    float4 m4 = make_float4(-INFINITY, -INFINITY, -INFINITY, -INFINITY);
    for (int i = beg + lane; i < end; i += 64) {
        float4 v = es4[i];
        m4.x = fmaxf(m4.x, v.x); m4.y = fmaxf(m4.y, v.y);
        m4.z = fmaxf(m4.z, v.z); m4.w = fmaxf(m4.w, v.w);
    }
    #pragma unroll
    for (int off = 32; off > 0; off >>= 1) {
        m4.x = fmaxf(m4.x, __shfl_xor(m4.x, off));
        m4.y = fmaxf(m4.y, __shfl_xor(m4.y, off));
        m4.z = fmaxf(m4.z, __shfl_xor(m4.z, off));
        m4.w = fmaxf(m4.w, __shfl_xor(m4.w, off));
    }
    // phase 2: per-head sum of exp
    float4 s4 = make_float4(0.f, 0.f, 0.f, 0.f);
    for (int i = beg + lane; i < end; i += 64) {
        float4 v = es4[i];
        s4.x += __expf(v.x - m4.x); s4.y += __expf(v.y - m4.y);
        s4.z += __expf(v.z - m4.z); s4.w += __expf(v.w - m4.w);
    }
    #pragma unroll
    for (int off = 32; off > 0; off >>= 1) {
        s4.x += __shfl_xor(s4.x, off);
        s4.y += __shfl_xor(s4.y, off);
        s4.z += __shfl_xor(s4.z, off);
        s4.w += __shfl_xor(s4.w, off);
    }

    const int fi = lane * 2;           // two consecutive features, same head
    const int h = lane >> 4;           // fi / 32
    const float m  = (h == 0) ? m4.x : (h == 1) ? m4.y : (h == 2) ? m4.z : m4.w;
    const float sv = (h == 0) ? s4.x : (h == 1) ? s4.y : (h == 2) ? s4.z : s4.w;
    const float inv = 1.f / fmaxf(sv, 1e-9f);

    // phase 3: aggregation — independent iterations, unrolled x4
    const float* esf = (const float*)es4;
    float acc0 = 0.f, acc1 = 0.f;
    int i = beg;
    for (; i + 4 <= end; i += 4) {
        const int sn0 = srcs[i], sn1 = srcs[i + 1], sn2 = srcs[i + 2], sn3 = srcs[i + 3];
        const float ev0 = esf[(i + 0) * 4 + h];
        const float ev1 = esf[(i + 1) * 4 + h];
        const float ev2 = esf[(i + 2) * 4 + h];
        const float ev3 = esf[(i + 3) * 4 + h];
        const __hip_bfloat162 f0 = *reinterpret_cast<const __hip_bfloat162*>(featb + (long)sn0 * 128 + fi);
        const __hip_bfloat162 f1 = *reinterpret_cast<const __hip_bfloat162*>(featb + (long)sn1 * 128 + fi);
        const __hip_bfloat162 f2 = *reinterpret_cast<const __hip_bfloat162*>(featb + (long)sn2 * 128 + fi);
        const __hip_bfloat162 f3 = *reinterpret_cast<const __hip_bfloat162*>(featb + (long)sn3 * 128 + fi);
        const float w0 = __expf(ev0 - m), w1 = __expf(ev1 - m);
        const float w2 = __expf(ev2 - m), w3 = __expf(ev3 - m);
        acc0 += w0 * __bfloat162float(f0.x); acc1 += w0 * __bfloat162float(f0.y);
        acc0 += w1 * __bfloat162float(f1.x); acc1 += w1 * __bfloat162float(f1.y);
        acc0 += w2 * __bfloat162float(f2.x); acc1 += w2 * __bfloat162float(f2.y);
        acc0 += w3 * __bfloat162float(f3.x); acc1 += w3 * __bfloat162float(f3.y);
    }
    for (; i < end; ++i) {
        const int sn = srcs[i];
        const float w = __expf(esf[i * 4 + h] - m);
        const __hip_bfloat162 f2 = *reinterpret_cast<const __hip_bfloat162*>(featb + (long)sn * 128 + fi);
        acc0 += w * __bfloat162float(f2.x);
        acc1 += w * __bfloat162float(f2.y);
    }

    float v0 = acc0 * inv, v1 = acc1 * inv;
    if constexpr (HAS_RES) {
        const float2 rr = *reinterpret_cast<const float2*>(res + (long)node * 128 + fi);
        v0 += rr.x; v1 += rr.y;
    }
    #pragma unroll
    for (int t = 0; t < NELU; ++t) {
        v0 = (v0 > 0.f) ? v0 : expm1f(v0);
        v1 = (v1 > 0.f) ? v1 : expm1f(v1);
    }
    __hip_bfloat162 o;
    o.x = __float2bfloat16(v0);
    o.y = __float2bfloat16(v1);
    *reinterpret_cast<__hip_bfloat162*>(out + (long)node * 128 + fi) = o;
}

// ---- node-centric softmax + aggregation, H=1, HD=47 (final layer) ----
__global__ __launch_bounds__(256) void node_agg1(
    const bf16* __restrict__ featb, const float* __restrict__ es1,
    const int* __restrict__ offs, const int* __restrict__ srcs,
    const float* __restrict__ res, float* __restrict__ out, int n) {
    const int node = (int)((blockIdx.x * blockDim.x + threadIdx.x) >> 6);
    const int lane = threadIdx.x & 63;
    if (node >= n) return;
    const int beg = offs[node], end = offs[node + 1];

    float m = -INFINITY;
    for (int i = beg + lane; i < end; i += 64) m = fmaxf(m, es1[i]);
    #pragma unroll
    for (int off = 32; off > 0; off >>= 1) m = fmaxf(m, __shfl_xor(m, off));
    float s = 0.f;
    for (int i = beg + lane; i < end; i += 64) s += __expf(es1[i] - m);
    #pragma unroll
    for (int off = 32; off > 0; off >>= 1) s += __shfl_xor(s, off);
    const float inv = 1.f / fmaxf(s, 1e-9f);

    const bool active = lane < NC;
    float acc = 0.f;
    int i = beg;
    for (; i + 4 <= end; i += 4) {
        const int sn0 = srcs[i], sn1 = srcs[i + 1], sn2 = srcs[i + 2], sn3 = srcs[i + 3];
        const float w0 = __expf(es1[i + 0] - m);
        const float w1 = __expf(es1[i + 1] - m);
        const float w2 = __expf(es1[i + 2] - m);
        const float w3 = __expf(es1[i + 3] - m);
        if (active) {
            acc += w0 * __bfloat162float(featb[(long)sn0 * NC + lane]);
            acc += w1 * __bfloat162float(featb[(long)sn1 * NC + lane]);
            acc += w2 * __bfloat162float(featb[(long)sn2 * NC + lane]);
            acc += w3 * __bfloat162float(featb[(long)sn3 * NC + lane]);
        }
    }
    for (; i < end; ++i) {
        const float w = __expf(es1[i] - m);
        if (active) acc += w * __bfloat162float(featb[(long)srcs[i] * NC + lane]);
    }
    if (active) {
        float v = acc * inv + res[(long)node * NC + lane];
        out[(long)node * NC + lane] = v;
    }
}

extern "C" void kernel_launch(void* const* d_in, const int* in_sizes, int n_in,
                              void* d_out, int out_size, void* d_ws, size_t ws_size,
                              hipStream_t stream) {
    const float* x     = (const float*)d_in[0];
    const float* W0    = (const float*)d_in[1];
    const float* al0   = (const float*)d_in[2];
    const float* ar0   = (const float*)d_in[3];
    const float* W1    = (const float*)d_in[4];
    const float* resW1 = (const float*)d_in[5];
    const float* al1   = (const float*)d_in[6];
    const float* ar1   = (const float*)d_in[7];
    const float* W2    = (const float*)d_in[8];
    const float* resW2 = (const float*)d_in[9];
    const float* al2   = (const float*)d_in[10];
    const float* ar2   = (const float*)d_in[11];
    const int*   src   = (const int*)d_in[12];
    const int*   dst   = (const int*)d_in[13];

    float* out    = (float*)d_out;
    float* logits = out;                 // [N, 47]
    float* e0     = out + (long)NN * NC; // [E, 4]
    float* e1     = e0 + (long)NE * NH;  // [E, 4]
    float* e2     = e1 + (long)NE * NH;  // [E, 1]

    char* p = (char*)d_ws;
    int* offs   = (int*)p; p += align256(sizeof(int) * (NN + 1));
    int* cursor = (int*)p; p += align256(sizeof(int) * NN);
    int* pos    = (int*)p; p += align256(sizeof(int) * NE);
    int* srcs   = (int*)p; p += align256(sizeof(int) * NE);
    float* el   = (float*)p; p += align256(sizeof(float) * NN * NH);
    float* er   = (float*)p; p += align256(sizeof(float) * NN * NH);
    float* feat = (float*)p; p += align256(sizeof(float) * (long)NN * 128);
    float* resb = (float*)p; p += align256(sizeof(float) * (long)NN * 128);
    bf16* featb = (bf16*)p; p += align256(sizeof(bf16) * (long)NN * 128);
    bf16* hb    = (bf16*)p; p += align256(sizeof(bf16) * (long)NN * 128);
    bf16* W0t   = (bf16*)p; p += align256(sizeof(bf16) * 128 * 256);
    bf16* W1t   = (bf16*)p; p += align256(sizeof(bf16) * 128 * 128);
    bf16* rW1t  = (bf16*)p; p += align256(sizeof(bf16) * 128 * 128);
    bf16* W2t   = (bf16*)p; p += align256(sizeof(bf16) * 48 * 128);
    bf16* rW2t  = (bf16*)p; p += align256(sizeof(bf16) * 48 * 128);
    // CSR-ordered scores alias the f32 feat buffer (disjoint lifetimes:
    // feat live gemm->attn_proj; es live edge_e->node_agg).
    float* es = feat;

    // ---- weight prep (independent of everything else) ----
    prep_w_all<<<dim3(128, 5), 256, 0, stream>>>(W0, W1, resW1, W2, resW2,
                                                 W0t, W1t, rW1t, W2t, rW2t);

    // ---- CSR by dst (rebuilt every call; deterministic structure) ----
    hipMemsetAsync(cursor, 0, sizeof(int) * NN, stream);
    count_k<<<(NE + 255) / 256, 256, 0, stream>>>(dst, cursor, NE);
    scan_k<<<1, 1024, 0, stream>>>(cursor, offs, NN);
    hipMemcpyAsync(cursor, offs, sizeof(int) * NN, hipMemcpyDeviceToDevice, stream);
    fill_k<<<(NE + 255) / 256, 256, 0, stream>>>(dst, src, cursor, pos, srcs, NE);

    const int gemmBlocks = (NN + 63) / 64;   // 469
    const int edgeBlocks = (NE + 255) / 256;
    const int nodeBlocks = NN / 4;           // one wave per node, 4 waves/block

    // ---- layer 0: x @ W0 -> feat f32 + featb bf16; ELU applied in node_agg ----
    gemm_mfma<true, 8, false><<<gemmBlocks, 256, 0, stream>>>(
        x, W0t, nullptr, feat, featb, nullptr, NN, FIN, 128);
    attn_proj<NH, DH><<<(NN * NH + 255) / 256, 256, 0, stream>>>(feat, al0, ar0, el, er, NN);
    edge_e<NH><<<edgeBlocks, 256, 0, stream>>>(el, er, src, dst, pos, e0, es, NE);
    node_agg4<1, false><<<nodeBlocks, 256, 0, stream>>>(featb, (const float4*)es, offs, srcs, nullptr, hb, NN);

    // ---- layer 1: dual GEMM (W1 -> feat/featb, resW1 -> resb), A = hb bf16 ----
    gemm_mfma<false, 8, true><<<gemmBlocks, 256, 0, stream>>>(
        hb, W1t, rW1t, feat, featb, resb, NN, 128, 128);
    attn_proj<NH, DH><<<(NN * NH + 255) / 256, 256, 0, stream>>>(feat, al1, ar1, el, er, NN);
    edge_e<NH><<<edgeBlocks, 256, 0, stream>>>(el, er, src, dst, pos, e1, es, NE);
    node_agg4<2, true><<<nodeBlocks, 256, 0, stream>>>(featb, (const float4*)es, offs, srcs, resb, hb, NN);

    // ---- final layer: dual GEMM (W2 -> feat/featb, resW2 -> resb), M=47 ----
    gemm_mfma<false, 3, true><<<gemmBlocks, 256, 0, stream>>>(
        hb, W2t, rW2t, feat, featb, resb, NN, 128, NC);
    attn_proj<1, NC><<<(NN + 255) / 256, 256, 0, stream>>>(feat, al2, ar2, el, er, NN);
    edge_e<1><<<edgeBlocks, 256, 0, stream>>>(el, er, src, dst, pos, e2, es, NE);
    node_agg1<<<nodeBlocks, 256, 0, stream>>>(featb, es, offs, srcs, resb, logits, NN);
}

// Round 5
// 259.170 us; speedup vs baseline: 2.1951x; 1.0488x over previous
//
#include <hip/hip_runtime.h>
#include <hip/hip_bf16.h>
#include <math.h>

// Problem constants
#define NN 30000
#define NE 480000
#define FIN 256
#define DH 32
#define NH 4
#define NC 47

typedef __attribute__((ext_vector_type(8))) short frag_ab;  // 8 bf16 (4 VGPR)
typedef __attribute__((ext_vector_type(4))) float f32x4;    // MFMA 16x16 accum
typedef __hip_bfloat16 bf16;

static inline size_t align256(size_t x) { return (x + 255) & ~(size_t)255; }

__device__ __forceinline__ short f2bf(float f) {
    union { float f; unsigned u; } c; c.f = f;
    unsigned r = (c.u + 0x7FFFu + ((c.u >> 16) & 1u)) >> 16;  // RNE
    return (short)r;
}

// ---------------- CSR build ----------------
__global__ void count_k(const int* __restrict__ dst, int* __restrict__ cnt, int E) {
    int e = blockIdx.x * blockDim.x + threadIdx.x;
    if (e < E) atomicAdd(&cnt[dst[e]], 1);
}

__global__ __launch_bounds__(1024) void scan_k(const int* __restrict__ cnt,
                                               int* __restrict__ offs, int n) {
    __shared__ int warp_sums[16];
    __shared__ int carry_s;
    const int lane = threadIdx.x & 63;
    const int wid = threadIdx.x >> 6;
    if (threadIdx.x == 0) carry_s = 0;
    __syncthreads();
    for (int base = 0; base < n; base += 1024) {
        int i = base + threadIdx.x;
        int v = (i < n) ? cnt[i] : 0;
        int x = v;
        #pragma unroll
        for (int off = 1; off < 64; off <<= 1) {
            int y = __shfl_up(x, off);
            if (lane >= off) x += y;
        }
        if (lane == 63) warp_sums[wid] = x;
        __syncthreads();
        if (wid == 0) {
            int ws = (lane < 16) ? warp_sums[lane] : 0;
            #pragma unroll
            for (int off = 1; off < 16; off <<= 1) {
                int y = __shfl_up(ws, off);
                if (lane >= off) ws += y;
            }
            if (lane < 16) warp_sums[lane] = ws;
        }
        __syncthreads();
        int wbase = (wid > 0) ? warp_sums[wid - 1] : 0;
        int incl = x + wbase + carry_s;
        if (i < n) offs[i] = incl - v;  // exclusive
        __syncthreads();
        if (threadIdx.x == 1023) carry_s = incl;
        __syncthreads();
    }
    if (threadIdx.x == 0) offs[n] = carry_s;
}

// writes pos[e] (CSR slot of edge e) and srcs[slot] (src id in CSR order)
__global__ void fill_k(const int* __restrict__ dst, const int* __restrict__ src,
                       int* __restrict__ cursor, int* __restrict__ pos,
                       int* __restrict__ srcs, int E) {
    int e = blockIdx.x * blockDim.x + threadIdx.x;
    if (e < E) {
        int p = atomicAdd(&cursor[dst[e]], 1);
        pos[e] = p;
        srcs[p] = src[e];
    }
}

// ---- weight prep: transposed bf16 weights, extended with el/er projection rows ----
// Layout: rows 0..M-1 = W^T; rows M..M+H-1 = W·al (head h); rows M+H..M+2H-1 = W·ar;
// remaining rows zero.  (For res weights: plain transpose + zero pad.)
__global__ void prep_w_all(const float* __restrict__ W0, const float* __restrict__ W1,
                           const float* __restrict__ rW1, const float* __restrict__ W2,
                           const float* __restrict__ rW2,
                           const float* __restrict__ al0, const float* __restrict__ ar0,
                           const float* __restrict__ al1, const float* __restrict__ ar1,
                           const float* __restrict__ al2, const float* __restrict__ ar2,
                           bf16* __restrict__ W0t, bf16* __restrict__ W1t,
                           bf16* __restrict__ rW1t, bf16* __restrict__ W2t,
                           bf16* __restrict__ rW2t) {
    const float *W, *al, *ar; bf16* Wt; int K, M, rows, H, D;
    switch (blockIdx.y) {
        case 0: W = W0;  Wt = W0t;  K = 256; M = 128; rows = 144; H = 4; D = 32; al = al0; ar = ar0; break;
        case 1: W = W1;  Wt = W1t;  K = 128; M = 128; rows = 144; H = 4; D = 32; al = al1; ar = ar1; break;
        case 2: W = rW1; Wt = rW1t; K = 128; M = 128; rows = 128; H = 0; D = 0;  al = nullptr; ar = nullptr; break;
        case 3: W = W2;  Wt = W2t;  K = 128; M = 47;  rows = 64;  H = 1; D = 47; al = al2; ar = ar2; break;
        default: W = rW2; Wt = rW2t; K = 128; M = 47; rows = 48;  H = 0; D = 0;  al = nullptr; ar = nullptr; break;
    }
    int i = blockIdx.x * 256 + threadIdx.x;
    if (i >= rows * K) return;
    int row = i / K, k = i - row * K;
    float v = 0.f;
    if (row < M) {
        v = W[(long)k * M + row];
    } else if (H > 0 && row < M + 2 * H) {
        int idx = row - M;
        int h = (idx < H) ? idx : idx - H;
        const float* a = (idx < H) ? al : ar;
        float s = 0.f;
        for (int d = 0; d < D; ++d) s += W[(long)k * M + h * D + d] * a[h * D + d];
        v = s;
    }
    Wt[i] = __float2bfloat16(v);
}

// ---- bf16 MFMA GEMM + fused attn projections ----
// C = A[N,K] @ B1t^T -> featb (bf16, cols<M), el (cols M..M+H-1), er (M+H..M+2H-1)
// optional dual: C2 (f32) = A @ B2t^T (res branch, cols<M).
// Block: 64 rows, 4 waves (wave w owns rows w*16..w*16+15).
template <bool A_F32, int NT1, int NT2, int HH>
__global__ __launch_bounds__(256) void gemm_mfma(
    const void* __restrict__ Av, const bf16* __restrict__ B1t,
    const bf16* __restrict__ B2t,
    bf16* __restrict__ C1b, float* __restrict__ el, float* __restrict__ er,
    float* __restrict__ C2, int N, int K, int M) {
    constexpr int LP = 56;  // 32 k + pad: rows 112B (16B-aligned, 2-way alias = free)
    __shared__ bf16 As[64][LP];
    __shared__ bf16 Bs1[NT1 * 16][LP];
    __shared__ bf16 Bs2[(NT2 > 0) ? NT2 * 16 : 1][LP];

    const int tid = threadIdx.x;
    const int lane = tid & 63;
    const int wid = tid >> 6;
    const int row0 = blockIdx.x * 64;
    const int l15 = lane & 15;
    const int kq = lane >> 4;          // k-quarter 0..3

    f32x4 acc1[NT1], acc2[(NT2 > 0) ? NT2 : 1];
    #pragma unroll
    for (int t = 0; t < NT1; ++t) acc1[t] = (f32x4){0.f, 0.f, 0.f, 0.f};
    if constexpr (NT2 > 0) {
        #pragma unroll
        for (int t = 0; t < NT2; ++t) acc2[t] = (f32x4){0.f, 0.f, 0.f, 0.f};
    }

    for (int k0 = 0; k0 < K; k0 += 32) {
        // stage A: 64 rows x 32 k (each thread: 8 contiguous k of one row)
        {
            const int r = tid >> 2, kk = (tid & 3) * 8;
            const int gr = row0 + r;
            if constexpr (A_F32) {
                const float* A = (const float*)Av;
                short tmp[8];
                if (gr < N) {
                    const float4 v0 = *(const float4*)&A[(long)gr * K + k0 + kk];
                    const float4 v1 = *(const float4*)&A[(long)gr * K + k0 + kk + 4];
                    tmp[0] = f2bf(v0.x); tmp[1] = f2bf(v0.y); tmp[2] = f2bf(v0.z); tmp[3] = f2bf(v0.w);
                    tmp[4] = f2bf(v1.x); tmp[5] = f2bf(v1.y); tmp[6] = f2bf(v1.z); tmp[7] = f2bf(v1.w);
                } else {
                    #pragma unroll
                    for (int j = 0; j < 8; ++j) tmp[j] = 0;
                }
                *(frag_ab*)&As[r][kk] = *(const frag_ab*)tmp;
            } else {
                const bf16* A = (const bf16*)Av;
                frag_ab v = {0, 0, 0, 0, 0, 0, 0, 0};
                if (gr < N) v = *(const frag_ab*)&A[(long)gr * K + k0 + kk];
                *(frag_ab*)&As[r][kk] = v;
            }
        }
        // stage B tiles (coalesced rows of transposed weights)
        for (int i = tid; i < NT1 * 64; i += 256) {
            const int c = i >> 2, kk = (i & 3) * 8;
            *(frag_ab*)&Bs1[c][kk] = *(const frag_ab*)&B1t[(long)c * K + k0 + kk];
        }
        if constexpr (NT2 > 0) {
            for (int i = tid; i < NT2 * 64; i += 256) {
                const int c = i >> 2, kk = (i & 3) * 8;
                *(frag_ab*)&Bs2[c][kk] = *(const frag_ab*)&B2t[(long)c * K + k0 + kk];
            }
        }
        __syncthreads();

        const frag_ab a = *(const frag_ab*)&As[wid * 16 + l15][kq * 8];
        #pragma unroll
        for (int t = 0; t < NT1; ++t) {
            const frag_ab b = *(const frag_ab*)&Bs1[t * 16 + l15][kq * 8];
            acc1[t] = __builtin_amdgcn_mfma_f32_16x16x32_bf16(a, b, acc1[t], 0, 0, 0);
        }
        if constexpr (NT2 > 0) {
            #pragma unroll
            for (int t = 0; t < NT2; ++t) {
                const frag_ab b = *(const frag_ab*)&Bs2[t * 16 + l15][kq * 8];
                acc2[t] = __builtin_amdgcn_mfma_f32_16x16x32_bf16(a, b, acc2[t], 0, 0, 0);
            }
        }
        __syncthreads();
    }

    // epilogue: D row = (lane>>4)*4 + reg, col = lane&15
    const int r0 = row0 + wid * 16 + kq * 4;
    #pragma unroll
    for (int t = 0; t < NT1; ++t) {
        const int c = t * 16 + l15;
        #pragma unroll
        for (int reg = 0; reg < 4; ++reg) {
            const int r = r0 + reg;
            if (r >= N) continue;
            const float v = acc1[t][reg];
            if (c < M) {
                C1b[(long)r * M + c] = __float2bfloat16(v);
            } else if (c < M + HH) {
                el[(long)r * HH + (c - M)] = v;
            } else if (c < M + 2 * HH) {
                er[(long)r * HH + (c - M - HH)] = v;
            }
        }
    }
    if constexpr (NT2 > 0) {
        #pragma unroll
        for (int t = 0; t < NT2; ++t) {
            const int c = t * 16 + l15;
            if (c >= M) continue;
            #pragma unroll
            for (int reg = 0; reg < 4; ++reg) {
                const int r = r0 + reg;
                if (r < N) C2[(long)r * M + c] = acc2[t][reg];
            }
        }
    }
}

// ---- edge scores e = leaky_relu(el[src]+er[dst]); dual write: edge order + CSR order ----
template <int H>
__global__ void edge_e(const float* __restrict__ el, const float* __restrict__ er,
                       const int* __restrict__ src, const int* __restrict__ dst,
                       const int* __restrict__ pos,
                       float* __restrict__ e_out, float* __restrict__ es, int E) {
    int e = blockIdx.x * blockDim.x + threadIdx.x;
    if (e >= E) return;
    int s = src[e], d = dst[e], p = pos[e];
    if constexpr (H == 4) {
        float4 a = *reinterpret_cast<const float4*>(el + s * 4);
        float4 b = *reinterpret_cast<const float4*>(er + d * 4);
        float4 v;
        v.x = a.x + b.x; v.y = a.y + b.y; v.z = a.z + b.z; v.w = a.w + b.w;
        v.x = (v.x >= 0.f) ? v.x : 0.2f * v.x;
        v.y = (v.y >= 0.f) ? v.y : 0.2f * v.y;
        v.z = (v.z >= 0.f) ? v.z : 0.2f * v.z;
        v.w = (v.w >= 0.f) ? v.w : 0.2f * v.w;
        *reinterpret_cast<float4*>(e_out + e * 4) = v;
        *reinterpret_cast<float4*>(es + p * 4) = v;
    } else {
        float v = el[s] + er[d];
        v = (v >= 0.f) ? v : 0.2f * v;
        e_out[e] = v;
        es[p] = v;
    }
}

// ---- node-centric softmax + aggregation, one wave/node, H=4 D=32 (HD=128) ----
// out is bf16 (next layer's GEMM A input); NELU applied before cast.
template <int NELU, bool HAS_RES>
__global__ __launch_bounds__(256) void node_agg4(
    const bf16* __restrict__ featb, const float4* __restrict__ es4,
    const int* __restrict__ offs, const int* __restrict__ srcs,
    const float* __restrict__ res, bf16* __restrict__ out, int n) {
    const int node = (int)((blockIdx.x * blockDim.x + threadIdx.x) >> 6);
    const int lane = threadIdx.x & 63;
    if (node >= n) return;
    const int beg = offs[node], end = offs[node + 1];

    // phase 1: per-head max (lane-parallel, coalesced CSR-ordered scores)
    float4 m4 = make_float4(-INFINITY, -INFINITY, -INFINITY, -INFINITY);
    for (int i = beg + lane; i < end; i += 64) {
        float4 v = es4[i];
        m4.x = fmaxf(m4.x, v.x); m4.y = fmaxf(m4.y, v.y);
        m4.z = fmaxf(m4.z, v.z); m4.w = fmaxf(m4.w, v.w);
    }
    #pragma unroll
    for (int off = 32; off > 0; off >>= 1) {
        m4.x = fmaxf(m4.x, __shfl_xor(m4.x, off));
        m4.y = fmaxf(m4.y, __shfl_xor(m4.y, off));
        m4.z = fmaxf(m4.z, __shfl_xor(m4.z, off));
        m4.w = fmaxf(m4.w, __shfl_xor(m4.w, off));
    }
    // phase 2: per-head sum of exp
    float4 s4 = make_float4(0.f, 0.f, 0.f, 0.f);
    for (int i = beg + lane; i < end; i += 64) {
        float4 v = es4[i];
        s4.x += __expf(v.x - m4.x); s4.y += __expf(v.y - m4.y);
        s4.z += __expf(v.z - m4.z); s4.w += __expf(v.w - m4.w);
    }
    #pragma unroll
    for (int off = 32; off > 0; off >>= 1) {
        s4.x += __shfl_xor(s4.x, off);
        s4.y += __shfl_xor(s4.y, off);
        s4.z += __shfl_xor(s4.z, off);
        s4.w += __shfl_xor(s4.w, off);
    }

    const int fi = lane * 2;           // two consecutive features, same head
    const int h = lane >> 4;           // fi / 32
    const float m  = (h == 0) ? m4.x : (h == 1) ? m4.y : (h == 2) ? m4.z : m4.w;
    const float sv = (h == 0) ? s4.x : (h == 1) ? s4.y : (h == 2) ? s4.z : s4.w;
    const float inv = 1.f / fmaxf(sv, 1e-9f);

    // phase 3: aggregation — independent iterations, unrolled x4
    const float* esf = (const float*)es4;
    float acc0 = 0.f, acc1 = 0.f;
    int i = beg;
    for (; i + 4 <= end; i += 4) {
        const int sn0 = srcs[i], sn1 = srcs[i + 1], sn2 = srcs[i + 2], sn3 = srcs[i + 3];
        const float ev0 = esf[(i + 0) * 4 + h];
        const float ev1 = esf[(i + 1) * 4 + h];
        const float ev2 = esf[(i + 2) * 4 + h];
        const float ev3 = esf[(i + 3) * 4 + h];
        const __hip_bfloat162 f0 = *reinterpret_cast<const __hip_bfloat162*>(featb + (long)sn0 * 128 + fi);
        const __hip_bfloat162 f1 = *reinterpret_cast<const __hip_bfloat162*>(featb + (long)sn1 * 128 + fi);
        const __hip_bfloat162 f2 = *reinterpret_cast<const __hip_bfloat162*>(featb + (long)sn2 * 128 + fi);
        const __hip_bfloat162 f3 = *reinterpret_cast<const __hip_bfloat162*>(featb + (long)sn3 * 128 + fi);
        const float w0 = __expf(ev0 - m), w1 = __expf(ev1 - m);
        const float w2 = __expf(ev2 - m), w3 = __expf(ev3 - m);
        acc0 += w0 * __bfloat162float(f0.x); acc1 += w0 * __bfloat162float(f0.y);
        acc0 += w1 * __bfloat162float(f1.x); acc1 += w1 * __bfloat162float(f1.y);
        acc0 += w2 * __bfloat162float(f2.x); acc1 += w2 * __bfloat162float(f2.y);
        acc0 += w3 * __bfloat162float(f3.x); acc1 += w3 * __bfloat162float(f3.y);
    }
    for (; i < end; ++i) {
        const int sn = srcs[i];
        const float w = __expf(esf[i * 4 + h] - m);
        const __hip_bfloat162 f2 = *reinterpret_cast<const __hip_bfloat162*>(featb + (long)sn * 128 + fi);
        acc0 += w * __bfloat162float(f2.x);
        acc1 += w * __bfloat162float(f2.y);
    }

    float v0 = acc0 * inv, v1 = acc1 * inv;
    if constexpr (HAS_RES) {
        const float2 rr = *reinterpret_cast<const float2*>(res + (long)node * 128 + fi);
        v0 += rr.x; v1 += rr.y;
    }
    #pragma unroll
    for (int t = 0; t < NELU; ++t) {
        v0 = (v0 > 0.f) ? v0 : expm1f(v0);
        v1 = (v1 > 0.f) ? v1 : expm1f(v1);
    }
    __hip_bfloat162 o;
    o.x = __float2bfloat16(v0);
    o.y = __float2bfloat16(v1);
    *reinterpret_cast<__hip_bfloat162*>(out + (long)node * 128 + fi) = o;
}

// ---- node-centric softmax + aggregation, H=1, HD=47 (final layer) ----
__global__ __launch_bounds__(256) void node_agg1(
    const bf16* __restrict__ featb, const float* __restrict__ es1,
    const int* __restrict__ offs, const int* __restrict__ srcs,
    const float* __restrict__ res, float* __restrict__ out, int n) {
    const int node = (int)((blockIdx.x * blockDim.x + threadIdx.x) >> 6);
    const int lane = threadIdx.x & 63;
    if (node >= n) return;
    const int beg = offs[node], end = offs[node + 1];

    float m = -INFINITY;
    for (int i = beg + lane; i < end; i += 64) m = fmaxf(m, es1[i]);
    #pragma unroll
    for (int off = 32; off > 0; off >>= 1) m = fmaxf(m, __shfl_xor(m, off));
    float s = 0.f;
    for (int i = beg + lane; i < end; i += 64) s += __expf(es1[i] - m);
    #pragma unroll
    for (int off = 32; off > 0; off >>= 1) s += __shfl_xor(s, off);
    const float inv = 1.f / fmaxf(s, 1e-9f);

    const bool active = lane < NC;
    float acc = 0.f;
    int i = beg;
    for (; i + 4 <= end; i += 4) {
        const int sn0 = srcs[i], sn1 = srcs[i + 1], sn2 = srcs[i + 2], sn3 = srcs[i + 3];
        const float w0 = __expf(es1[i + 0] - m);
        const float w1 = __expf(es1[i + 1] - m);
        const float w2 = __expf(es1[i + 2] - m);
        const float w3 = __expf(es1[i + 3] - m);
        if (active) {
            acc += w0 * __bfloat162float(featb[(long)sn0 * NC + lane]);
            acc += w1 * __bfloat162float(featb[(long)sn1 * NC + lane]);
            acc += w2 * __bfloat162float(featb[(long)sn2 * NC + lane]);
            acc += w3 * __bfloat162float(featb[(long)sn3 * NC + lane]);
        }
    }
    for (; i < end; ++i) {
        const float w = __expf(es1[i] - m);
        if (active) acc += w * __bfloat162float(featb[(long)srcs[i] * NC + lane]);
    }
    if (active) {
        float v = acc * inv + res[(long)node * NC + lane];
        out[(long)node * NC + lane] = v;
    }
}

extern "C" void kernel_launch(void* const* d_in, const int* in_sizes, int n_in,
                              void* d_out, int out_size, void* d_ws, size_t ws_size,
                              hipStream_t stream) {
    const float* x     = (const float*)d_in[0];
    const float* W0    = (const float*)d_in[1];
    const float* al0   = (const float*)d_in[2];
    const float* ar0   = (const float*)d_in[3];
    const float* W1    = (const float*)d_in[4];
    const float* resW1 = (const float*)d_in[5];
    const float* al1   = (const float*)d_in[6];
    const float* ar1   = (const float*)d_in[7];
    const float* W2    = (const float*)d_in[8];
    const float* resW2 = (const float*)d_in[9];
    const float* al2   = (const float*)d_in[10];
    const float* ar2   = (const float*)d_in[11];
    const int*   src   = (const int*)d_in[12];
    const int*   dst   = (const int*)d_in[13];

    float* out    = (float*)d_out;
    float* logits = out;                 // [N, 47]
    float* e0     = out + (long)NN * NC; // [E, 4]
    float* e1     = e0 + (long)NE * NH;  // [E, 4]
    float* e2     = e1 + (long)NE * NH;  // [E, 1]

    char* p = (char*)d_ws;
    int* offs   = (int*)p; p += align256(sizeof(int) * (NN + 1));
    int* cursor = (int*)p; p += align256(sizeof(int) * NN);
    int* pos    = (int*)p; p += align256(sizeof(int) * NE);
    int* srcs   = (int*)p; p += align256(sizeof(int) * NE);
    float* el   = (float*)p; p += align256(sizeof(float) * NN * NH);
    float* er   = (float*)p; p += align256(sizeof(float) * NN * NH);
    float* es   = (float*)p; p += align256(sizeof(float) * (long)NE * NH);
    float* resb = (float*)p; p += align256(sizeof(float) * (long)NN * 128);
    bf16* featb = (bf16*)p; p += align256(sizeof(bf16) * (long)NN * 128);
    bf16* hb    = (bf16*)p; p += align256(sizeof(bf16) * (long)NN * 128);
    bf16* W0t   = (bf16*)p; p += align256(sizeof(bf16) * 144 * 256);
    bf16* W1t   = (bf16*)p; p += align256(sizeof(bf16) * 144 * 128);
    bf16* rW1t  = (bf16*)p; p += align256(sizeof(bf16) * 128 * 128);
    bf16* W2t   = (bf16*)p; p += align256(sizeof(bf16) * 64 * 128);
    bf16* rW2t  = (bf16*)p; p += align256(sizeof(bf16) * 48 * 128);

    // ---- weight prep (transpose + fused attn-projection columns) ----
    prep_w_all<<<dim3(144, 5), 256, 0, stream>>>(W0, W1, resW1, W2, resW2,
                                                 al0, ar0, al1, ar1, al2, ar2,
                                                 W0t, W1t, rW1t, W2t, rW2t);

    // ---- CSR by dst (rebuilt every call; deterministic structure) ----
    hipMemsetAsync(cursor, 0, sizeof(int) * NN, stream);
    count_k<<<(NE + 255) / 256, 256, 0, stream>>>(dst, cursor, NE);
    scan_k<<<1, 1024, 0, stream>>>(cursor, offs, NN);
    hipMemcpyAsync(cursor, offs, sizeof(int) * NN, hipMemcpyDeviceToDevice, stream);
    fill_k<<<(NE + 255) / 256, 256, 0, stream>>>(dst, src, cursor, pos, srcs, NE);

    const int gemmBlocks = (NN + 63) / 64;   // 469
    const int edgeBlocks = (NE + 255) / 256;
    const int nodeBlocks = NN / 4;           // one wave per node, 4 waves/block

    // ---- layer 0: x @ [W0|wl0|wr0] -> featb bf16 + el + er ----
    gemm_mfma<true, 9, 0, NH><<<gemmBlocks, 256, 0, stream>>>(
        x, W0t, nullptr, featb, el, er, nullptr, NN, FIN, 128);
    edge_e<NH><<<edgeBlocks, 256, 0, stream>>>(el, er, src, dst, pos, e0, es, NE);
    node_agg4<1, false><<<nodeBlocks, 256, 0, stream>>>(featb, (const float4*)es, offs, srcs, nullptr, hb, NN);

    // ---- layer 1: hb @ [W1|wl1|wr1] + hb @ resW1 -> featb/el/er + resb ----
    gemm_mfma<false, 9, 8, NH><<<gemmBlocks, 256, 0, stream>>>(
        hb, W1t, rW1t, featb, el, er, resb, NN, 128, 128);
    edge_e<NH><<<edgeBlocks, 256, 0, stream>>>(el, er, src, dst, pos, e1, es, NE);
    node_agg4<2, true><<<nodeBlocks, 256, 0, stream>>>(featb, (const float4*)es, offs, srcs, resb, hb, NN);

    // ---- final layer: hb @ [W2|wl2|wr2] + hb @ resW2 (M=47) ----
    gemm_mfma<false, 4, 3, 1><<<gemmBlocks, 256, 0, stream>>>(
        hb, W2t, rW2t, featb, el, er, resb, NN, 128, NC);
    edge_e<1><<<edgeBlocks, 256, 0, stream>>>(el, er, src, dst, pos, e2, es, NE);
    node_agg1<<<nodeBlocks, 256, 0, stream>>>(featb, es, offs, srcs, resb, logits, NN);
}